// Round 7
// baseline (11223.161 us; speedup 1.0000x reference)
//
#include <hip/hip_runtime.h>
#include <math.h>

#define B_  256
#define T_  1024
#define S_  8
#define H_  256
#define L_  32
#define RH_ 32
#define NC  16   // clusters (batch groups of 16)
#define CB  16   // blocks per cluster (16 H-rows each)
#define MB  16   // batch rows per cluster
#define NR  16   // H rows per block
#define TPB 256  // 4 waves: w0=layer0 MFMA(+h0 stage), w1=layer1 x-side MFMA(+h1 stage), w2=layer1 h-side MFMA, w3=LN/dt
#define FH  (B_*H_)   // 65536 floats per parity plane

typedef __attribute__((ext_vector_type(8))) short bf16x8;   // 8 bf16 = 4 VGPRs
typedef __attribute__((ext_vector_type(4))) float f32x4;
typedef unsigned long long ull;

__device__ __forceinline__ void split_bf16(float v, short& hi, short& lo) {
    unsigned ub = __float_as_uint(v);
    float hf = __uint_as_float(ub & 0xffff0000u);   // truncate to bf16 (exact residual below)
    hi = (short)(ub >> 16);
    lo = (short)(__float_as_uint(v - hf) >> 16);    // residual truncated to bf16: ~2^-16 rel total
}

// Build A-fragments from a staged LDS plane (row stride 260 floats: 16B-aligned
// rows, ds_read_b128 at throughput floor) and run the 3-term MFMA chain.
// Values/ops/order identical to r0's LLC-load version -> bit-identical results.
__device__ __forceinline__ void lds_frag_mfma(
    const float (&sh)[16][260], int n, int quad,
    const bf16x8 (&whi)[2][8], const bf16x8 (&wlo)[2][8],
    f32x4& accg, f32x4& accf)
{
    #pragma unroll
    for (int kb = 0; kb < 8; ++kb) {
        const float* sp = &sh[n][kb*32 + quad*8];
        bf16x8 ahi, alo;
        #pragma unroll
        for (int e = 0; e < 8; ++e) {
            short h_, l_;
            split_bf16(sp[e], h_, l_);
            ahi[e] = h_; alo[e] = l_;
        }
        accg = __builtin_amdgcn_mfma_f32_16x16x32_bf16(ahi, whi[0][kb], accg, 0,0,0);
        accg = __builtin_amdgcn_mfma_f32_16x16x32_bf16(alo, whi[0][kb], accg, 0,0,0);
        accg = __builtin_amdgcn_mfma_f32_16x16x32_bf16(ahi, wlo[0][kb], accg, 0,0,0);
        accf = __builtin_amdgcn_mfma_f32_16x16x32_bf16(ahi, whi[1][kb], accf, 0,0,0);
        accf = __builtin_amdgcn_mfma_f32_16x16x32_bf16(alo, whi[1][kb], accf, 0,0,0);
        accf = __builtin_amdgcn_mfma_f32_16x16x32_bf16(ahi, wlo[1][kb], accf, 0,0,0);
    }
}

__global__ void __launch_bounds__(TPB, 1)
liquid_cfc_mfma(const float* __restrict__ xs,      // [B,T,S]
                const float* __restrict__ tstamp,  // [B,T]
                const float* __restrict__ ln_g, const float* __restrict__ ln_b,
                const float* __restrict__ bb_w0, const float* __restrict__ bb_b0,
                const float* __restrict__ gx_w0, const float* __restrict__ gx_b0,
                const float* __restrict__ gh_w0, const float* __restrict__ gb0,
                const float* __restrict__ lt0,
                const float* __restrict__ bb_w1, const float* __restrict__ bb_b1,
                const float* __restrict__ gx_w1, const float* __restrict__ gx_b1,
                const float* __restrict__ gh_w1, const float* __restrict__ gb1,
                const float* __restrict__ lt1,
                const float* __restrict__ lp_w, const float* __restrict__ lp_b,
                const float* __restrict__ r1_w, const float* __restrict__ r1_b,
                const float* __restrict__ r2_w, const float* __restrict__ r2_b,
                float* __restrict__ out,
                int*   bar,     // [NC*64] cluster counters, 256B apart (r0 structure)
                float* h0pub,   // [2][B][H] fp32, device-coherent exchange (r0 format)
                float* h1pub,   // [2][B][H]
                float* latg)    // [B][L]
{
    const int tid  = threadIdx.x, lane = tid & 63, wid = tid >> 6;
    const int blk  = blockIdx.x,  c = blk >> 4,    j  = blk & 15;
    const int b0   = c * MB,      r0 = j * NR;
    const int n    = lane & 15,   quad = lane >> 4;
    int* cnt = &bar[c * 64];

    // Staged exchange planes: the cluster's 16x256 fp32 h-slice, re-staged every
    // epoch with fully-coalesced loads. Row stride 260 (pad 4): rows 16B-aligned
    // (b128-able), fragment-read bank pattern at the b128 throughput floor.
    __shared__ float s_h0[16][260];
    __shared__ float s_h1[16][260];
    __shared__ float s_xn[16][9];            // +1 pad
    __shared__ float s_dt[2][16];            // dt double-buffered by epoch parity
    __shared__ float s_gx0[16][9], s_bb0x[16][9];
    __shared__ float s_bg0[16], s_bf0[16], s_sp0[16];
    __shared__ float s_bg1[16], s_bf1[16], s_sp1[16];
    __shared__ float s_pg[16][17], s_pf[16][17];   // wave1 -> wave2 partials

    // ---- one-time LDS init ----
    if (tid < 16) {
        s_bg0[tid] = gx_b0[r0+tid] + gb0[r0+tid];
        s_bf0[tid] = bb_b0[r0+tid];
        s_sp0[tid] = log1pf(expf(lt0[r0+tid]));
        s_bg1[tid] = gx_b1[r0+tid] + gb1[r0+tid];
        s_bf1[tid] = bb_b1[r0+tid];
        s_sp1[tid] = log1pf(expf(lt1[r0+tid]));
    }
    if (tid < 128) {
        int r = tid >> 3, s = tid & 7;
        s_gx0[r][s]  = gx_w0[(r0+r)*S_ + s];
        s_bb0x[r][s] = bb_w0[(r0+r)*(S_+H_) + s];
    }

    // ---- one-time: weight slices -> bf16 hi/lo MFMA B-fragments in registers ----
    // wave0: gh_w0 (g), bb_w0 h-part (f)   [A = h0]
    // wave1: gx_w1 (g), bb_w1 x-part (f)   [A = h0]
    // wave2: gh_w1 (g), bb_w1 h-part (f)   [A = h1]
    bf16x8 whi[2][8], wlo[2][8];
    if (wid < 3) {
        const float* base[2]; int st[2], of[2];
        if (wid == 0) { base[0]=gh_w0; st[0]=H_;   of[0]=0;  base[1]=bb_w0; st[1]=S_+H_; of[1]=S_; }
        else if (wid == 1) { base[0]=gx_w1; st[0]=H_; of[0]=0; base[1]=bb_w1; st[1]=2*H_; of[1]=0; }
        else { base[0]=gh_w1; st[0]=H_; of[0]=0; base[1]=bb_w1; st[1]=2*H_; of[1]=H_; }
        int row = r0 + n;
        for (int mt = 0; mt < 2; ++mt) {
            const float* bp = base[mt] + (size_t)row * st[mt] + of[mt];
            for (int kb = 0; kb < 8; ++kb) {
                const float* sp = bp + kb*32 + quad*8;
                #pragma unroll
                for (int jj = 0; jj < 8; ++jj) {
                    short h_, l_;
                    split_bf16(sp[jj], h_, l_);
                    whi[mt][kb][jj] = h_; wlo[mt][kb][jj] = l_;
                }
            }
        }
    }
    float lngv[8], lnbv[8];
    if (wid == 3 && lane < 16) {
        #pragma unroll
        for (int s = 0; s < 8; ++s) { lngv[s] = ln_g[s]; lnbv[s] = ln_b[s]; }
    }
    float h0own[4] = {0.f,0.f,0.f,0.f};   // wave0: own slice of h0 (fp32 exact recurrent state)
    float h1own[4] = {0.f,0.f,0.f,0.f};   // wave2: own slice of h1
    float tsPrev = 0.f;
    __syncthreads();

    // ---- main loop: epoch t computes layer0(step t) and layer1(step t-1) ----
    for (int t = 0; t <= T_; ++t) {
        const int p = t & 1, q = 1 - p;

        // phase A (pre-sync#0): coalesced staging of the exchange planes + LN.
        // Each instruction: 64 lanes x 8B contiguous = 512B, 1 request/line,
        // zero redundancy. Plane q was published at t-1 and barrier(t-1)
        // guarantees visibility; it is next rewritten at t+1 (after barrier(t)),
        // so the stage/read window is hazard-free (same protocol as r0).
        if (wid == 0) {   // h0[q]: needed by w0 (t<T_) and w1 (t>=1) -> every epoch
            const ull* src = (const ull*)(h0pub + (size_t)q*FH + (size_t)b0*H_);
            #pragma unroll
            for (int k2 = 0; k2 < 32; ++k2) {
                ull d = __hip_atomic_load(&src[k2*64 + lane],
                                          __ATOMIC_RELAXED, __HIP_MEMORY_SCOPE_AGENT);
                *(ull*)&s_h0[k2 >> 1][((k2 & 1) << 7) + lane*2] = d;
            }
        } else if (wid == 1 && t >= 1) {   // h1[q]: needed by w2 (t>=1)
            const ull* src = (const ull*)(h1pub + (size_t)q*FH + (size_t)b0*H_);
            #pragma unroll
            for (int k2 = 0; k2 < 32; ++k2) {
                ull d = __hip_atomic_load(&src[k2*64 + lane],
                                          __ATOMIC_RELAXED, __HIP_MEMORY_SCOPE_AGENT);
                *(ull*)&s_h1[k2 >> 1][((k2 & 1) << 7) + lane*2] = d;
            }
        } else if (wid == 3 && t < T_ && lane < 16) {
            int m = lane;
            const float* xp = xs + ((size_t)(b0+m) * T_ + t) * S_;
            float v[8]; float mu = 0.f;
            #pragma unroll
            for (int s = 0; s < 8; ++s) { v[s] = xp[s]; mu += v[s]; }
            mu *= 0.125f;
            float var = 0.f;
            #pragma unroll
            for (int s = 0; s < 8; ++s) { float d = v[s] - mu; var += d * d; }
            var *= 0.125f;
            float rstd = rsqrtf(var + 1e-5f);
            #pragma unroll
            for (int s = 0; s < 8; ++s) s_xn[m][s] = (v[s] - mu) * rstd * lngv[s] + lnbv[s];
            float ts = tstamp[(size_t)(b0+m) * T_ + t];
            float dt = (t == 0) ? 1.0f : fmaxf(ts - tsPrev, 1e-6f);
            tsPrev = ts;
            s_dt[p][m] = dt;
        }
        __syncthreads();   // sync#0: staged planes + xn/dt visible

        // phase B: fragment builds from LDS + 3-term MFMA (bit-identical to r0)
        f32x4 accg = {0.f,0.f,0.f,0.f}, accf = {0.f,0.f,0.f,0.f};
        if (wid == 0 && t < T_) {
            lds_frag_mfma(s_h0, n, quad, whi, wlo, accg, accf);
        } else if (wid == 1 && t >= 1) {
            lds_frag_mfma(s_h0, n, quad, whi, wlo, accg, accf);   // dedup: LDS copy
            #pragma unroll
            for (int i = 0; i < 4; ++i) {
                s_pg[quad*4+i][n] = accg[i];
                s_pf[quad*4+i][n] = accf[i];
            }
        } else if (wid == 2 && t >= 1) {
            lds_frag_mfma(s_h1, n, quad, whi, wlo, accg, accf);
        }
        __syncthreads();   // sync#1: wave1 partials ready

        // wave0 epilogue: layer-0 cell for step t, publish h0[t] (fp32, r0 path)
        if (wid == 0 && t < T_) {
            #pragma unroll
            for (int i = 0; i < 4; ++i) {
                int m = quad*4 + i;
                float aG = accg[i] + s_bg0[n];
                float aF = accf[i] + s_bf0[n];
                #pragma unroll
                for (int s = 0; s < 8; ++s) {
                    float xv = s_xn[m][s];
                    aG += s_gx0[n][s] * xv;
                    aF += s_bb0x[n][s] * xv;
                }
                float g   = 1.f / (1.f + expf(-aG));
                float f   = tanhf(aF);
                float dec = expf(-s_dt[p][m] * (s_sp0[n] + fabsf(g)));
                h0own[i]  = dec * h0own[i] + (1.f - dec) * f;
                __hip_atomic_store(&h0pub[(size_t)p*FH + (size_t)(b0+m)*H_ + (r0+n)],
                                   h0own[i], __ATOMIC_RELAXED, __HIP_MEMORY_SCOPE_AGENT);
            }
        }
        // wave2 epilogue: layer-1 cell for step t-1, publish h1[t-1]
        if (wid == 2 && t >= 1) {
            #pragma unroll
            for (int i = 0; i < 4; ++i) {
                int m = quad*4 + i;
                float aG = accg[i] + s_pg[m][n] + s_bg1[n];
                float aF = accf[i] + s_pf[m][n] + s_bf1[n];
                float g   = 1.f / (1.f + expf(-aG));
                float f   = tanhf(aF);
                float dec = expf(-s_dt[q][m] * (s_sp1[n] + fabsf(g)));
                h1own[i]  = dec * h1own[i] + (1.f - dec) * f;
                __hip_atomic_store(&h1pub[(size_t)p*FH + (size_t)(b0+m)*H_ + (r0+n)],
                                   h1own[i], __ATOMIC_RELAXED, __HIP_MEMORY_SCOPE_AGENT);
            }
        }

        // cluster barrier (r0 structure, fastest measured): syncthreads drains all
        // waves' stores (vmcnt(0) before s_barrier); device-scope write-through
        // stores are then globally visible -> no cache flush needed.
        __syncthreads();
        if (tid == 0) {
            __hip_atomic_fetch_add(cnt, 1, __ATOMIC_RELAXED, __HIP_MEMORY_SCOPE_AGENT);
            int tgt = (t + 1) * CB;
            while (__hip_atomic_load(cnt, __ATOMIC_RELAXED, __HIP_MEMORY_SCOPE_AGENT) < tgt) { }
        }
        __syncthreads();
    }

    // ---- latent head: h1 final = step T-1, published at epoch T (parity 0) ----
    if (tid < 32) {
        int lb = tid >> 1;
        int l  = j*2 + (tid & 1);
        float* hsrc = h1pub + (size_t)(b0+lb) * H_;   // parity 0 plane
        float acc = lp_b[l];
        #pragma unroll 8
        for (int k = 0; k < H_; ++k)
            acc += __hip_atomic_load(&hsrc[k], __ATOMIC_RELAXED, __HIP_MEMORY_SCOPE_AGENT)
                   * lp_w[l*H_ + k];
        float lat = tanhf(acc);
        out[(b0+lb)*L_ + l] = lat;
        __hip_atomic_store(&latg[(b0+lb)*L_ + l], lat,
                           __ATOMIC_RELAXED, __HIP_MEMORY_SCOPE_AGENT);
    }
    __syncthreads();
    if (tid == 0) {
        __hip_atomic_fetch_add(cnt, 1, __ATOMIC_RELAXED, __HIP_MEMORY_SCOPE_AGENT);
        int tgt = (T_ + 2) * CB;
        while (__hip_atomic_load(cnt, __ATOMIC_RELAXED, __HIP_MEMORY_SCOPE_AGENT) < tgt) { }
    }
    __syncthreads();

    // ---- risk head (block 0 of each cluster) ----
    if (j == 0 && tid < 16) {
        float latv[L_];
        #pragma unroll
        for (int l = 0; l < L_; ++l)
            latv[l] = __hip_atomic_load(&latg[(b0+tid)*L_ + l],
                                        __ATOMIC_RELAXED, __HIP_MEMORY_SCOPE_AGENT);
        float acc2 = r2_b[0];
        for (int j2 = 0; j2 < RH_; ++j2) {
            float z = r1_b[j2];
            #pragma unroll
            for (int l = 0; l < L_; ++l) z += r1_w[j2*L_ + l] * latv[l];
            float hid = 0.5f * z * (1.f + erff(z * 0.70710678118654752f)); // exact GELU
            acc2 += r2_w[j2] * hid;
        }
        out[B_*L_ + b0 + tid] = 1.f / (1.f + expf(-acc2));
    }
}

extern "C" void kernel_launch(void* const* d_in, const int* in_sizes, int n_in,
                              void* d_out, int out_size, void* d_ws, size_t ws_size,
                              hipStream_t stream) {
    (void)in_sizes; (void)n_in; (void)out_size; (void)ws_size;
    const float* xs     = (const float*)d_in[0];
    const float* tstamp = (const float*)d_in[1];
    const float* ln_g   = (const float*)d_in[2];
    const float* ln_b   = (const float*)d_in[3];
    const float* bb_w0  = (const float*)d_in[4];
    const float* bb_b0  = (const float*)d_in[5];
    const float* gx_w0  = (const float*)d_in[6];
    const float* gx_b0  = (const float*)d_in[7];
    const float* gh_w0  = (const float*)d_in[8];
    const float* gb0    = (const float*)d_in[9];
    const float* lt0    = (const float*)d_in[10];
    const float* bb_w1  = (const float*)d_in[11];
    const float* bb_b1  = (const float*)d_in[12];
    const float* gx_w1  = (const float*)d_in[13];
    const float* gx_b1  = (const float*)d_in[14];
    const float* gh_w1  = (const float*)d_in[15];
    const float* gb1    = (const float*)d_in[16];
    const float* lt1    = (const float*)d_in[17];
    const float* lp_w   = (const float*)d_in[18];
    const float* lp_b   = (const float*)d_in[19];
    const float* r1_w   = (const float*)d_in[20];
    const float* r1_b   = (const float*)d_in[21];
    const float* r2_w   = (const float*)d_in[22];
    const float* r2_b   = (const float*)d_in[23];

    // ws carve: bar 4KB | h0pub 2*FH | h1pub 2*FH | latg B*L   (r0 layout)
    uint8_t* w = (uint8_t*)d_ws;
    int*   bar   = (int*)w;
    float* h0pub = (float*)(w + 4096);
    float* h1pub = h0pub + 2 * FH;
    float* latg  = h1pub + 2 * FH;

    // zero flags + both parities of h state (epoch 0/1 read zeros; ws poisoned 0xAA)
    hipMemsetAsync(d_ws, 0, 4096 + (size_t)(4 * FH + B_ * L_) * sizeof(float), stream);

    liquid_cfc_mfma<<<dim3(NC * CB), dim3(TPB), 0, stream>>>(
        xs, tstamp, ln_g, ln_b,
        bb_w0, bb_b0, gx_w0, gx_b0, gh_w0, gb0, lt0,
        bb_w1, bb_b1, gx_w1, gx_b1, gh_w1, gb1, lt1,
        lp_w, lp_b, r1_w, r1_b, r2_w, r2_b,
        (float*)d_out, bar, h0pub, h1pub, latg);
}

// Round 8
// 4915.953 us; speedup vs baseline: 2.2830x; 2.2830x over previous
//
#include <hip/hip_runtime.h>
#include <math.h>

#define B_  256
#define T_  1024
#define S_  8
#define H_  256
#define L_  32
#define RH_ 32
#define NC  16   // clusters (batch groups of 16)
#define CB  16   // blocks per cluster (16 H-rows each)
#define MB  16   // batch rows per cluster
#define NR  16   // H rows per block
#define TPB 256  // 4 waves: w0=layer0 MFMA, w1=layer1 x-side MFMA, w2=layer1 h-side MFMA, w3=LN/dt
#define FH  (B_*H_)   // 65536 floats per parity plane
#define CS  (MB*H_)   // 4096 floats: one cluster's slice of a plane

typedef __attribute__((ext_vector_type(8))) short bf16x8;   // 8 bf16 = 4 VGPRs
typedef __attribute__((ext_vector_type(4))) float f32x4;
typedef unsigned long long ull;

__device__ __forceinline__ void split_bf16(float v, short& hi, short& lo) {
    unsigned ub = __float_as_uint(v);
    float hf = __uint_as_float(ub & 0xffff0000u);   // truncate to bf16 (exact residual below)
    hi = (short)(ub >> 16);
    lo = (short)(__float_as_uint(v - hf) >> 16);    // residual truncated to bf16: ~2^-16 rel total
}

// Exchange planes are stored in MFMA-FRAGMENT ORDER per cluster:
//   element (batch mb, k) at offset ((kb*4 + quad_k)*16 + mb)*8 + e,
//   kb = k>>5, quad_k = (k>>3)&3, e = k&7.
// Consumer lane (n,quad) [lane = quad*16+n] needs h[batch=n][k=kb*32+quad*8+e],
// whose offset is kb*512 + lane*8 + e  ->  per kb, the wave reads
// base + lane*32B: fully contiguous 2KB, 1 request/line, zero redundancy
// (vs r0's scattered layout: 4x line re-requests). Values and unpack are
// IDENTICAL to r0 -> bit-identical results.
__device__ __forceinline__ void exch_mfma(
    const float* src, int lane,
    const bf16x8 (&whi)[2][8], const bf16x8 (&wlo)[2][8],
    f32x4& accg, f32x4& accf)
{
    const ull* hsrc = (const ull*)src;
    ull araw[32];
    #pragma unroll
    for (int u = 0; u < 32; ++u) {
        int kb = u >> 2, uu = u & 3;
        araw[u] = __hip_atomic_load(&hsrc[kb*256 + lane*4 + uu],
                                    __ATOMIC_RELAXED, __HIP_MEMORY_SCOPE_AGENT);
    }
    #pragma unroll
    for (int kb = 0; kb < 8; ++kb) {
        bf16x8 ahi, alo;
        #pragma unroll
        for (int uu = 0; uu < 4; ++uu) {
            ull d = araw[kb*4 + uu];
            float f0 = __uint_as_float((unsigned)d);
            float f1 = __uint_as_float((unsigned)(d >> 32));
            short h_, l_;
            split_bf16(f0, h_, l_); ahi[uu*2]   = h_; alo[uu*2]   = l_;
            split_bf16(f1, h_, l_); ahi[uu*2+1] = h_; alo[uu*2+1] = l_;
        }
        accg = __builtin_amdgcn_mfma_f32_16x16x32_bf16(ahi, whi[0][kb], accg, 0,0,0);
        accg = __builtin_amdgcn_mfma_f32_16x16x32_bf16(alo, whi[0][kb], accg, 0,0,0);
        accg = __builtin_amdgcn_mfma_f32_16x16x32_bf16(ahi, wlo[0][kb], accg, 0,0,0);
        accf = __builtin_amdgcn_mfma_f32_16x16x32_bf16(ahi, whi[1][kb], accf, 0,0,0);
        accf = __builtin_amdgcn_mfma_f32_16x16x32_bf16(alo, whi[1][kb], accf, 0,0,0);
        accf = __builtin_amdgcn_mfma_f32_16x16x32_bf16(ahi, wlo[1][kb], accf, 0,0,0);
    }
}

__global__ void __launch_bounds__(TPB, 1)
liquid_cfc_mfma(const float* __restrict__ xs,      // [B,T,S]
                const float* __restrict__ tstamp,  // [B,T]
                const float* __restrict__ ln_g, const float* __restrict__ ln_b,
                const float* __restrict__ bb_w0, const float* __restrict__ bb_b0,
                const float* __restrict__ gx_w0, const float* __restrict__ gx_b0,
                const float* __restrict__ gh_w0, const float* __restrict__ gb0,
                const float* __restrict__ lt0,
                const float* __restrict__ bb_w1, const float* __restrict__ bb_b1,
                const float* __restrict__ gx_w1, const float* __restrict__ gx_b1,
                const float* __restrict__ gh_w1, const float* __restrict__ gb1,
                const float* __restrict__ lt1,
                const float* __restrict__ lp_w, const float* __restrict__ lp_b,
                const float* __restrict__ r1_w, const float* __restrict__ r1_b,
                const float* __restrict__ r2_w, const float* __restrict__ r2_b,
                float* __restrict__ out,
                int*   bar,     // [NC*64] cluster counters, 256B apart (r0 structure)
                float* h0pub,   // [2][NC][CS] fp32, FRAGMENT-ORDER exchange
                float* h1pub,   // [2][NC][CS]
                float* h1fin,   // [B][H] fp32 final h1, row-major (latent tail)
                float* latg)    // [B][L]
{
    const int tid  = threadIdx.x, lane = tid & 63, wid = tid >> 6;
    const int blk  = blockIdx.x,  c = blk >> 4,    j  = blk & 15;
    const int b0   = c * MB,      r0 = j * NR;
    const int n    = lane & 15,   quad = lane >> 4;
    int* cnt = &bar[c * 64];

    // Producer-side fragment-layout constants for k = r0 + n = j*16 + n:
    const int kbp = j >> 1;                       // k >> 5
    const int qkp = ((j & 1) << 1) | (n >> 3);    // (k >> 3) & 3
    const int ebp = n & 7;                        // k & 7
    // offset for batch slot mb: ((kbp*4+qkp)*16 + mb)*8 + ebp
    const int pbase = ((kbp*4 + qkp)*16)*8 + ebp;

    __shared__ float s_xn[16][9];            // +1 pad (r4-r6 proven)
    __shared__ float s_dt[2][16];            // dt double-buffered by epoch parity
    __shared__ float s_gx0[16][9], s_bb0x[16][9];
    __shared__ float s_bg0[16], s_bf0[16], s_sp0[16];
    __shared__ float s_bg1[16], s_bf1[16], s_sp1[16];
    __shared__ float s_pg[16][17], s_pf[16][17];   // wave1 -> wave2 partials

    // ---- one-time LDS init ----
    if (tid < 16) {
        s_bg0[tid] = gx_b0[r0+tid] + gb0[r0+tid];
        s_bf0[tid] = bb_b0[r0+tid];
        s_sp0[tid] = log1pf(expf(lt0[r0+tid]));
        s_bg1[tid] = gx_b1[r0+tid] + gb1[r0+tid];
        s_bf1[tid] = bb_b1[r0+tid];
        s_sp1[tid] = log1pf(expf(lt1[r0+tid]));
    }
    if (tid < 128) {
        int r = tid >> 3, s = tid & 7;
        s_gx0[r][s]  = gx_w0[(r0+r)*S_ + s];
        s_bb0x[r][s] = bb_w0[(r0+r)*(S_+H_) + s];
    }

    // ---- one-time: weight slices -> bf16 hi/lo MFMA B-fragments in registers ----
    // wave0: gh_w0 (g), bb_w0 h-part (f)   [A = h0]
    // wave1: gx_w1 (g), bb_w1 x-part (f)   [A = h0]
    // wave2: gh_w1 (g), bb_w1 h-part (f)   [A = h1]
    bf16x8 whi[2][8], wlo[2][8];
    if (wid < 3) {
        const float* base[2]; int st[2], of[2];
        if (wid == 0) { base[0]=gh_w0; st[0]=H_;   of[0]=0;  base[1]=bb_w0; st[1]=S_+H_; of[1]=S_; }
        else if (wid == 1) { base[0]=gx_w1; st[0]=H_; of[0]=0; base[1]=bb_w1; st[1]=2*H_; of[1]=0; }
        else { base[0]=gh_w1; st[0]=H_; of[0]=0; base[1]=bb_w1; st[1]=2*H_; of[1]=H_; }
        int row = r0 + n;
        for (int mt = 0; mt < 2; ++mt) {
            const float* bp = base[mt] + (size_t)row * st[mt] + of[mt];
            for (int kb = 0; kb < 8; ++kb) {
                const float* sp = bp + kb*32 + quad*8;
                #pragma unroll
                for (int jj = 0; jj < 8; ++jj) {
                    short h_, l_;
                    split_bf16(sp[jj], h_, l_);
                    whi[mt][kb][jj] = h_; wlo[mt][kb][jj] = l_;
                }
            }
        }
    }
    float lngv[8], lnbv[8];
    if (wid == 3 && lane < 16) {
        #pragma unroll
        for (int s = 0; s < 8; ++s) { lngv[s] = ln_g[s]; lnbv[s] = ln_b[s]; }
    }
    float h0own[4] = {0.f,0.f,0.f,0.f};   // wave0: own slice of h0 (fp32 exact recurrent state)
    float h1own[4] = {0.f,0.f,0.f,0.f};   // wave2: own slice of h1
    float tsPrev = 0.f;
    __syncthreads();

    // ---- main loop: epoch t computes layer0(step t) and layer1(step t-1) ----
    for (int t = 0; t <= T_; ++t) {
        const int p = t & 1, q = 1 - p;
        const bool act = (wid == 0 || wid == 3) ? (t < T_) : (t >= 1);

        // wave3: layernorm x_t + dt
        if (wid == 3 && act && lane < 16) {
            int m = lane;
            const float* xp = xs + ((size_t)(b0+m) * T_ + t) * S_;
            float v[8]; float mu = 0.f;
            #pragma unroll
            for (int s = 0; s < 8; ++s) { v[s] = xp[s]; mu += v[s]; }
            mu *= 0.125f;
            float var = 0.f;
            #pragma unroll
            for (int s = 0; s < 8; ++s) { float d = v[s] - mu; var += d * d; }
            var *= 0.125f;
            float rstd = rsqrtf(var + 1e-5f);
            #pragma unroll
            for (int s = 0; s < 8; ++s) s_xn[m][s] = (v[s] - mu) * rstd * lngv[s] + lnbv[s];
            float ts = tstamp[(size_t)(b0+m) * T_ + t];
            float dt = (t == 0) ? 1.0f : fmaxf(ts - tsPrev, 1e-6f);
            tsPrev = ts;
            s_dt[p][m] = dt;
        }

        // waves 0-2: coalesced fragment-order A loads, split, 3-term MFMA
        f32x4 accg = {0.f,0.f,0.f,0.f}, accf = {0.f,0.f,0.f,0.f};
        if (wid < 3 && act) {
            const float* plane = (wid == 2) ? h1pub : h0pub;
            exch_mfma(plane + (size_t)q*FH + (size_t)c*CS, lane,
                      whi, wlo, accg, accf);
            if (wid == 1) {
                #pragma unroll
                for (int i = 0; i < 4; ++i) {
                    s_pg[quad*4+i][n] = accg[i];
                    s_pf[quad*4+i][n] = accf[i];
                }
            }
        }
        __syncthreads();   // sync#1: xn/dt ready; wave1 partials ready

        // wave0 epilogue: layer-0 cell for step t, publish h0[t] (fragment order)
        if (wid == 0 && act) {
            #pragma unroll
            for (int i = 0; i < 4; ++i) {
                int m = quad*4 + i;
                float aG = accg[i] + s_bg0[n];
                float aF = accf[i] + s_bf0[n];
                #pragma unroll
                for (int s = 0; s < 8; ++s) {
                    float xv = s_xn[m][s];
                    aG += s_gx0[n][s] * xv;
                    aF += s_bb0x[n][s] * xv;
                }
                float g   = 1.f / (1.f + expf(-aG));
                float f   = tanhf(aF);
                float dec = expf(-s_dt[p][m] * (s_sp0[n] + fabsf(g)));
                h0own[i]  = dec * h0own[i] + (1.f - dec) * f;
                __hip_atomic_store(&h0pub[(size_t)p*FH + (size_t)c*CS + pbase + m*8],
                                   h0own[i], __ATOMIC_RELAXED, __HIP_MEMORY_SCOPE_AGENT);
            }
        }
        // wave2 epilogue: layer-1 cell for step t-1, publish h1[t-1] (fragment order)
        if (wid == 2 && t >= 1) {
            #pragma unroll
            for (int i = 0; i < 4; ++i) {
                int m = quad*4 + i;
                float aG = accg[i] + s_pg[m][n] + s_bg1[n];
                float aF = accf[i] + s_pf[m][n] + s_bf1[n];
                float g   = 1.f / (1.f + expf(-aG));
                float f   = tanhf(aF);
                float dec = expf(-s_dt[q][m] * (s_sp1[n] + fabsf(g)));
                h1own[i]  = dec * h1own[i] + (1.f - dec) * f;
                __hip_atomic_store(&h1pub[(size_t)p*FH + (size_t)c*CS + pbase + m*8],
                                   h1own[i], __ATOMIC_RELAXED, __HIP_MEMORY_SCOPE_AGENT);
                if (t == T_)   // bit-exact fp32 row-major copy of final h1 for the tail
                    __hip_atomic_store(&h1fin[(size_t)(b0+m)*H_ + (r0+n)], h1own[i],
                                       __ATOMIC_RELAXED, __HIP_MEMORY_SCOPE_AGENT);
            }
        }

        // cluster barrier (r0 structure, fastest measured): syncthreads drains all
        // waves' stores (vmcnt(0) before s_barrier); device-scope write-through
        // stores are then globally visible -> no cache flush needed.
        __syncthreads();
        if (tid == 0) {
            __hip_atomic_fetch_add(cnt, 1, __ATOMIC_RELAXED, __HIP_MEMORY_SCOPE_AGENT);
            int tgt = (t + 1) * CB;
            while (__hip_atomic_load(cnt, __ATOMIC_RELAXED, __HIP_MEMORY_SCOPE_AGENT) < tgt) { }
        }
        __syncthreads();
    }

    // ---- latent head: h1 final = step T-1, fp32 row-major in h1fin ----
    if (tid < 32) {
        int lb = tid >> 1;
        int l  = j*2 + (tid & 1);
        const float* hsrc = h1fin + (size_t)(b0+lb) * H_;
        float acc = lp_b[l];
        #pragma unroll 8
        for (int k = 0; k < H_; ++k)
            acc += __hip_atomic_load(&hsrc[k], __ATOMIC_RELAXED, __HIP_MEMORY_SCOPE_AGENT)
                   * lp_w[l*H_ + k];
        float lat = tanhf(acc);
        out[(b0+lb)*L_ + l] = lat;
        __hip_atomic_store(&latg[(b0+lb)*L_ + l], lat,
                           __ATOMIC_RELAXED, __HIP_MEMORY_SCOPE_AGENT);
    }
    __syncthreads();
    if (tid == 0) {
        __hip_atomic_fetch_add(cnt, 1, __ATOMIC_RELAXED, __HIP_MEMORY_SCOPE_AGENT);
        int tgt = (T_ + 2) * CB;
        while (__hip_atomic_load(cnt, __ATOMIC_RELAXED, __HIP_MEMORY_SCOPE_AGENT) < tgt) { }
    }
    __syncthreads();

    // ---- risk head (block 0 of each cluster) ----
    if (j == 0 && tid < 16) {
        float latv[L_];
        #pragma unroll
        for (int l = 0; l < L_; ++l)
            latv[l] = __hip_atomic_load(&latg[(b0+tid)*L_ + l],
                                        __ATOMIC_RELAXED, __HIP_MEMORY_SCOPE_AGENT);
        float acc2 = r2_b[0];
        for (int j2 = 0; j2 < RH_; ++j2) {
            float z = r1_b[j2];
            #pragma unroll
            for (int l = 0; l < L_; ++l) z += r1_w[j2*L_ + l] * latv[l];
            float hid = 0.5f * z * (1.f + erff(z * 0.70710678118654752f)); // exact GELU
            acc2 += r2_w[j2] * hid;
        }
        out[B_*L_ + b0 + tid] = 1.f / (1.f + expf(-acc2));
    }
}

extern "C" void kernel_launch(void* const* d_in, const int* in_sizes, int n_in,
                              void* d_out, int out_size, void* d_ws, size_t ws_size,
                              hipStream_t stream) {
    (void)in_sizes; (void)n_in; (void)out_size; (void)ws_size;
    const float* xs     = (const float*)d_in[0];
    const float* tstamp = (const float*)d_in[1];
    const float* ln_g   = (const float*)d_in[2];
    const float* ln_b   = (const float*)d_in[3];
    const float* bb_w0  = (const float*)d_in[4];
    const float* bb_b0  = (const float*)d_in[5];
    const float* gx_w0  = (const float*)d_in[6];
    const float* gx_b0  = (const float*)d_in[7];
    const float* gh_w0  = (const float*)d_in[8];
    const float* gb0    = (const float*)d_in[9];
    const float* lt0    = (const float*)d_in[10];
    const float* bb_w1  = (const float*)d_in[11];
    const float* bb_b1  = (const float*)d_in[12];
    const float* gx_w1  = (const float*)d_in[13];
    const float* gx_b1  = (const float*)d_in[14];
    const float* gh_w1  = (const float*)d_in[15];
    const float* gb1    = (const float*)d_in[16];
    const float* lt1    = (const float*)d_in[17];
    const float* lp_w   = (const float*)d_in[18];
    const float* lp_b   = (const float*)d_in[19];
    const float* r1_w   = (const float*)d_in[20];
    const float* r1_b   = (const float*)d_in[21];
    const float* r2_w   = (const float*)d_in[22];
    const float* r2_b   = (const float*)d_in[23];

    // ws carve: bar 4KB | h0pub 2*FH | h1pub 2*FH | h1fin FH | latg B*L
    uint8_t* w = (uint8_t*)d_ws;
    int*   bar   = (int*)w;
    float* h0pub = (float*)(w + 4096);
    float* h1pub = h0pub + 2 * FH;
    float* h1fin = h1pub + 2 * FH;
    float* latg  = h1fin + FH;

    // zero flags + both parities of h state + h1fin (epoch 0/1 read zeros)
    hipMemsetAsync(d_ws, 0,
                   4096 + (size_t)(5 * FH + B_ * L_) * sizeof(float), stream);

    liquid_cfc_mfma<<<dim3(NC * CB), dim3(TPB), 0, stream>>>(
        xs, tstamp, ln_g, ln_b,
        bb_w0, bb_b0, gx_w0, gx_b0, gh_w0, gb0, lt0,
        bb_w1, bb_b1, gx_w1, gx_b1, gh_w1, gb1, lt1,
        lp_w, lp_b, r1_w, r1_b, r2_w, r2_b,
        (float*)d_out, bar, h0pub, h1pub, h1fin, latg);
}